// Round 12
// baseline (460.299 us; speedup 1.0000x reference)
//
#include <hip/hip_runtime.h>

typedef unsigned int u32;
typedef unsigned short u16;
typedef __attribute__((ext_vector_type(8))) short short8;
typedef __attribute__((ext_vector_type(4))) float f32x4;

__device__ __forceinline__ float sigmoidf_(float x){
  return 1.f / (1.f + __expf(-x));
}
__device__ __forceinline__ u16 f2bf(float f){
  union { float f; u32 i; } v; v.f = f;
  u32 r = v.i + 0x7fffu + ((v.i >> 16) & 1u);
  return (u16)(r >> 16);
}
__device__ __forceinline__ float bf2f(u32 u){
  union { float f; u32 i; } v; v.i = (u & 0xffffu) << 16; return v.f;
}
// fast softplus: max(x,0) + log(1+exp(-|x|)); abs err < 6e-8 vs log1pf
__device__ __forceinline__ float softplus_(float x){
  return fmaxf(x, 0.f) + __logf(1.f + __expf(-fabsf(x)));
}

// ---------------- setup (swizzle 4 weight sets + LN fold) + prep (pad X) in ONE launch ----------------
// blocks [0,577): weight swizzle + fold; blocks [577,1097): prep rows (independent work).
__global__ __launch_bounds__(256) void k_setup(
    const float* __restrict__ w0, u16* __restrict__ h0, u16* __restrict__ l0,
    const float* __restrict__ w1, u16* __restrict__ h1, u16* __restrict__ l1,
    const float* __restrict__ w2, u16* __restrict__ h2, u16* __restrict__ l2,
    const float* __restrict__ w3, u16* __restrict__ h3, u16* __restrict__ l3,
    const float* __restrict__ Wa, const float* __restrict__ lnwa, const float* __restrict__ lnba,
    float* __restrict__ W2a, float* __restrict__ B2a,
    const float* __restrict__ Wb, const float* __restrict__ lnwb, const float* __restrict__ lnbb,
    float* __restrict__ W2b, float* __restrict__ B2b,
    const float* __restrict__ src, u16* __restrict__ PH, u16* __restrict__ PL,
    u16* __restrict__ BPH, u16* __restrict__ BPL)
{
  __shared__ float ld[64 * 129];
  int bx = blockIdx.x;
  int tid = threadIdx.x;
  if (bx < 577){
    int gidx = bx * 256 + tid;   // -> 147712
    if (gidx < 147456){
      int set = gidx / 36864;
      int idx = gidx - set * 36864;
      const float* w; u16* WH; u16* WL;
      if (set == 0){ w = w0; WH = h0; WL = l0; }
      else if (set == 1){ w = w1; WH = h1; WL = l1; }
      else if (set == 2){ w = w2; WH = h2; WL = l2; }
      else { w = w3; WH = h3; WL = l3; }
      int j    = idx & 7;
      int lane = (idx >> 3) & 63;
      int nt   = (idx >> 9) & 3;
      int kc   = (idx >> 11) & 1;
      int t    = idx >> 12;           // 0..8
      int ic = kc * 32 + ((lane >> 4) & 3) * 8 + j;
      int oc = nt * 16 + (lane & 15);
      float v = w[(oc * 64 + ic) * 9 + t];
      u16 h = f2bf(v);
      u16 l = f2bf(v - bf2f(h));
      WH[idx] = h; WL[idx] = l;
    } else {
      int i = gidx - 147456;          // 128 fold rows
      if (i >= 128) return;
      int m = i >> 6, j = i & 63;
      const float* W   = m ? Wb   : Wa;
      const float* lnw = m ? lnwb : lnwa;
      const float* lnb = m ? lnbb : lnba;
      float* W2 = m ? W2b : W2a;
      float* B2 = m ? B2b : B2a;
      float bias = 0.f;
#pragma unroll
      for (int k4 = 0; k4 < 16; k4++){
        float4 wv = *(const float4*)&W[j * 64 + k4 * 4];
        float4 gw = *(const float4*)&lnw[k4 * 4];
        float4 gb = *(const float4*)&lnb[k4 * 4];
        W2[j * 64 + k4 * 4 + 0] = wv.x * gw.x;
        W2[j * 64 + k4 * 4 + 1] = wv.y * gw.y;
        W2[j * 64 + k4 * 4 + 2] = wv.z * gw.z;
        W2[j * 64 + k4 * 4 + 3] = wv.w * gw.w;
        bias = fmaf(wv.x, gb.x, bias);
        bias = fmaf(wv.y, gb.y, bias);
        bias = fmaf(wv.z, gb.z, bias);
        bias = fmaf(wv.w, gb.w, bias);
      }
      B2[j] = bias;
    }
  } else {
    // prep: NCHW fp32 -> padded NHWC bf16 hi/lo (+ zero borders of stage-2 pad)
    int bid2 = bx - 577;
    int yp = bid2 % 130;
    int b  = bid2 / 130;
    int ys = yp - 1;
    if (yp == 0 || yp == 129){
      for (int i = tid; i < 130 * 64; i += 256){
        int x = i >> 6, c = i & 63;
        size_t o = (((size_t)b * 130 + yp) * 130 + x) * 64 + c;
        BPH[o] = 0; BPL[o] = 0;
      }
    } else {
      for (int i = tid; i < 128; i += 256){
        int x = (i >= 64) ? 129 : 0, c = i & 63;
        size_t o = (((size_t)b * 130 + yp) * 130 + x) * 64 + c;
        BPH[o] = 0; BPL[o] = 0;
      }
    }
    if ((u32)ys < 128u){
      for (int i = tid; i < 8192; i += 256){
        int c = i >> 7, x = i & 127;
        ld[c * 129 + x] = src[((size_t)(b * 64 + c) * 128 + ys) * 128 + x];
      }
    }
    __syncthreads();
    for (int i = tid; i < 130 * 64; i += 256){
      int xp = i >> 6, c = i & 63;
      float v = 0.f;
      if ((u32)ys < 128u && (u32)(xp - 1) < 128u) v = ld[c * 129 + (xp - 1)];
      u16 h = f2bf(v);
      u16 l = f2bf(v - bf2f(h));
      size_t o = (((size_t)b * 130 + yp) * 130 + xp) * 64 + c;
      PH[o] = h; PL[o] = l;
    }
  }
}

// ---------------- prep with fused bilinear upsample 64->128 (+ zero borders of next pad) ----------------
// LDS stride padded to 65: read bank = (c + x) % 32 -> 2-way (free).
__global__ __launch_bounds__(256) void k_prepup(const float* __restrict__ FEAT,
                                                u16* __restrict__ PH, u16* __restrict__ PL,
                                                u16* __restrict__ BPH, u16* __restrict__ BPL){
  __shared__ float ld0[64 * 65], ld1[64 * 65];
  int yp = blockIdx.x;
  int b  = blockIdx.y;
  int ys = yp - 1;
  int tid = threadIdx.x;
  if (yp == 0 || yp == 129){
    for (int i = tid; i < 130 * 64; i += 256){
      int x = i >> 6, c = i & 63;
      size_t o = (((size_t)b * 130 + yp) * 130 + x) * 64 + c;
      BPH[o] = 0; BPL[o] = 0;
    }
  } else {
    for (int i = tid; i < 128; i += 256){
      int x = (i >= 64) ? 129 : 0, c = i & 63;
      size_t o = (((size_t)b * 130 + yp) * 130 + x) * 64 + c;
      BPH[o] = 0; BPL[o] = 0;
    }
  }
  float wy = 0.f;
  if ((u32)ys < 128u){
    float ay = 0.5f * ys - 0.25f;
    int fy = (int)floorf(ay); wy = ay - fy;
    int y0s = fy < 0 ? 0 : fy, y1s = fy + 1 > 63 ? 63 : fy + 1;
    for (int i = tid; i < 1024; i += 256){
      int c = i >> 4, x4 = (i & 15) * 4;
      float4 a0 = *(const float4*)&FEAT[((size_t)(b * 64 + c) * 64 + y0s) * 64 + x4];
      float4 a1 = *(const float4*)&FEAT[((size_t)(b * 64 + c) * 64 + y1s) * 64 + x4];
      ld0[c * 65 + x4 + 0] = a0.x; ld0[c * 65 + x4 + 1] = a0.y;
      ld0[c * 65 + x4 + 2] = a0.z; ld0[c * 65 + x4 + 3] = a0.w;
      ld1[c * 65 + x4 + 0] = a1.x; ld1[c * 65 + x4 + 1] = a1.y;
      ld1[c * 65 + x4 + 2] = a1.z; ld1[c * 65 + x4 + 3] = a1.w;
    }
  }
  __syncthreads();
  for (int i = tid; i < 130 * 64; i += 256){
    int xp = i >> 6, c = i & 63;
    float v = 0.f;
    int xs = xp - 1;
    if ((u32)ys < 128u && (u32)xs < 128u){
      float ax = 0.5f * xs - 0.25f;
      int fx = (int)floorf(ax); float wx = ax - fx;
      int x0s = fx < 0 ? 0 : fx, x1s = fx + 1 > 63 ? 63 : fx + 1;
      float v0 = (1.f - wx) * ld0[c * 65 + x0s] + wx * ld0[c * 65 + x1s];
      float v1 = (1.f - wx) * ld1[c * 65 + x0s] + wx * ld1[c * 65 + x1s];
      v = (1.f - wy) * v0 + wy * v1;
    }
    u16 h = f2bf(v);
    u16 l = f2bf(v - bf2f(h));
    size_t o = (((size_t)b * 130 + yp) * 130 + xp) * 64 + c;
    PH[o] = h; PL[o] = l;
  }
}

// ---------------- MFMA conv3x3 64->64 (16x8 px tile, 2 blocks/CU) ----------------
// grid (8,16,4): 16x8 px tile, 64 oc. block 256 = 4 waves; wave w = rows {2w,2w+1}.
// mode 0: relu -> padded bf16 h/l.  mode 1: fp32 NCHW (+resid).
// mode 2: (+resid) -> fused 2x2-avg tokenize + LN -> T, NT.
__global__ __launch_bounds__(256) void k_convm(
    const u16* __restrict__ PH, const u16* __restrict__ PL,
    const u16* __restrict__ WH, const u16* __restrict__ WL,
    const float* __restrict__ resid,
    u16* __restrict__ OBH, u16* __restrict__ OBL,
    float* __restrict__ OUTF, float* __restrict__ T, float* __restrict__ NT,
    int mode)
{
  __shared__ __align__(16) u32 smem[9024];   // stage 5760 | epi(+red) 9024
  u16* Ah_s = (u16*)smem;                    // 5760 u16: [10r][18c][32ic]
  u16* Al_s = Ah_s + 5760;
  int tid = threadIdx.x;
  int lane = tid & 63, w = tid >> 6;
  int quad = lane >> 4, lcol = lane & 15;
  int b = blockIdx.z, y0 = blockIdx.y * 8, x0 = blockIdx.x * 16;

  f32x4 acc[2][4];
#pragma unroll
  for (int mt = 0; mt < 2; mt++)
#pragma unroll
    for (int nt = 0; nt < 4; nt++)
      acc[mt][nt] = (f32x4){0.f, 0.f, 0.f, 0.f};

  for (int kc = 0; kc < 2; kc++){
    __syncthreads();
    for (int i = tid; i < 720; i += 256){
      int q = i & 3;
      int rc = i >> 2;
      int r = rc / 18, c = rc - r * 18;
      size_t so = (((size_t)b * 130 + y0 + r) * 130 + (x0 + c)) * 64 + kc * 32 + q * 8;
      int de = (r * 18 + c) * 32 + q * 8;
      *(uint4*)(Ah_s + de) = *(const uint4*)(PH + so);
      *(uint4*)(Al_s + de) = *(const uint4*)(PL + so);
    }
    __syncthreads();
#pragma unroll
    for (int t = 0; t < 9; t++){
      int dy = t / 3, dx = t - dy * 3;
      short8 bh[4], bl[4];
#pragma unroll
      for (int nt = 0; nt < 4; nt++){
        int o = ((t * 2 + kc) * 4 + nt) * 512 + lane * 8;
        bh[nt] = *(const short8*)(WH + o);
        bl[nt] = *(const short8*)(WL + o);
      }
      short8 ah[2], al[2];
#pragma unroll
      for (int mt = 0; mt < 2; mt++){
        int e = ((w * 2 + mt + dy) * 18 + (lcol + dx)) * 32 + quad * 8;
        ah[mt] = *(const short8*)(Ah_s + e);
        al[mt] = *(const short8*)(Al_s + e);
      }
#pragma unroll
      for (int mt = 0; mt < 2; mt++)
#pragma unroll
        for (int nt = 0; nt < 4; nt++){
          acc[mt][nt] = __builtin_amdgcn_mfma_f32_16x16x32_bf16(ah[mt], bh[nt], acc[mt][nt], 0, 0, 0);
          acc[mt][nt] = __builtin_amdgcn_mfma_f32_16x16x32_bf16(ah[mt], bl[nt], acc[mt][nt], 0, 0, 0);
          acc[mt][nt] = __builtin_amdgcn_mfma_f32_16x16x32_bf16(al[mt], bh[nt], acc[mt][nt], 0, 0, 0);
        }
    }
  }

  // epilogue. C-frag: col(lane&15)=oc-in-tile, row(quad*4+reg)=px-col.
  __syncthreads();
  if (mode == 0){
    u32* epi = smem;   // [px 128][oc 66]
#pragma unroll
    for (int mt = 0; mt < 2; mt++){
      int row = w * 2 + mt;
#pragma unroll
      for (int nt = 0; nt < 4; nt++){
#pragma unroll
        for (int reg = 0; reg < 4; reg++){
          float v = fmaxf(acc[mt][nt][reg], 0.f);
          u32 h = f2bf(v);
          u32 l = f2bf(v - bf2f(h));
          int ccol = quad * 4 + reg;
          int oc = nt * 16 + lcol;
          epi[(row * 16 + ccol) * 66 + oc] = h | (l << 16);
        }
      }
    }
    __syncthreads();
    for (int i = tid; i < 8192; i += 256){
      int px = i >> 6, oc = i & 63;
      int row = px >> 4, ccol = px & 15;
      u32 pk = epi[px * 66 + oc];
      size_t o = (((size_t)b * 130 + y0 + row + 1) * 130 + (x0 + ccol + 1)) * 64 + oc;
      OBH[o] = (u16)pk;
      OBL[o] = (u16)(pk >> 16);
    }
  } else {
    float* epi = (float*)smem;  // [oc 64][px 131]
#pragma unroll
    for (int mt = 0; mt < 2; mt++){
      int row = w * 2 + mt;
#pragma unroll
      for (int nt = 0; nt < 4; nt++){
#pragma unroll
        for (int reg = 0; reg < 4; reg++){
          int px = row * 16 + quad * 4 + reg;
          int oc = nt * 16 + lcol;
          epi[oc * 131 + px] = acc[mt][nt][reg];
        }
      }
    }
    __syncthreads();
    if (mode == 1){
      for (int i = tid; i < 8192; i += 256){
        int oc = i >> 7, px = i & 127;
        int row = px >> 4, c = px & 15;
        size_t o = (((size_t)b * 64 + oc) * 128 + y0 + row) * 128 + x0 + c;
        float v = epi[oc * 131 + px];
        if (resid) v += resid[o];
        OUTF[o] = v;
      }
    } else {
      // mode 2: add residual into LDS, then tokenize + LN
      for (int i = tid; i < 8192; i += 256){
        int oc = i >> 7, px = i & 127;
        int row = px >> 4, c = px & 15;
        size_t o = (((size_t)b * 64 + oc) * 128 + y0 + row) * 128 + x0 + c;
        epi[oc * 131 + px] += resid[o];
      }
      __syncthreads();
      float* redS  = (float*)smem + 8384;  // [32][9]
      float* redQ  = redS + 288;           // [32][9]
      float* stats = redQ + 288;           // [32][2]
      int token = tid & 31, cgrp = tid >> 5;
      int tr = token >> 3, tc = token & 7;
      float av[8]; float s = 0.f, q = 0.f;
      int p0 = (2 * tr) * 16 + 2 * tc;
#pragma unroll
      for (int j = 0; j < 8; j++){
        int c = cgrp * 8 + j;
        const float* ep = epi + c * 131;
        float v = 0.25f * (ep[p0] + ep[p0 + 1] + ep[p0 + 16] + ep[p0 + 17]);
        av[j] = v; s += v; q = fmaf(v, v, q);
      }
      redS[token * 9 + cgrp] = s;
      redQ[token * 9 + cgrp] = q;
      __syncthreads();
      if (tid < 32){
        float S = 0.f, Q = 0.f;
        for (int g = 0; g < 8; g++){ S += redS[tid * 9 + g]; Q += redQ[tid * 9 + g]; }
        float mu = S * (1.f / 64.f);
        float var = Q * (1.f / 64.f) - mu * mu;
        stats[tid * 2] = mu;
        stats[tid * 2 + 1] = rsqrtf(var + 1e-5f);
      }
      __syncthreads();
      float mu = stats[token * 2], inv = stats[token * 2 + 1];
      int l = (blockIdx.y * 4 + tr) * 64 + blockIdx.x * 8 + tc;
      size_t to = ((size_t)b * 4096 + l) * 64 + cgrp * 8;
#pragma unroll
      for (int j = 0; j < 8; j++){
        T[to + j] = av[j];
        NT[to + j] = (av[j] - mu) * inv;
      }
    }
  }
}

// ---------------- in_proj + fused dwconv/silu (both mambas) ----------------
// grid (256, 4, 2): x = 64-token tile, y = 64-col quarter (0,1 -> XC->U; 2,3 -> Z).
__global__ __launch_bounds__(256) void k_inprojdw(
    const float* __restrict__ NT,
    const float* __restrict__ W2a, const float* __restrict__ B2a,
    float* __restrict__ Ua, float* __restrict__ Za,
    const float* __restrict__ cwa, const float* __restrict__ cba,
    const float* __restrict__ W2b, const float* __restrict__ B2b,
    float* __restrict__ Ub, float* __restrict__ Zb,
    const float* __restrict__ cwb, const float* __restrict__ cbb)
{
  __shared__ float wL[64 * 68];
  __shared__ float xcs[67 * 68];
  int mz = blockIdx.z;
  const float* W2 = mz ? W2b : W2a;
  const float* B2 = mz ? B2b : B2a;
  float* U = mz ? Ub : Ua;
  float* Z  = mz ? Zb : Za;
  const float* cw = mz ? cwb : cwa;
  const float* cb = mz ? cbb : cba;
  int tid = threadIdx.x;
  int t0 = blockIdx.x * 64;
  int j0 = blockIdx.y * 64;
  for (int i = tid; i < 4096; i += 256){
    int jl = i >> 6, k = i & 63;
    wL[jl * 68 + k] = W2[(size_t)(j0 + jl) * 64 + k];
  }
  __syncthreads();
  int tq = tid >> 4, cg = tid & 15;
  const float* ntp = NT + (size_t)(t0 + tq * 4) * 64;
  float acc[4][4];
#pragma unroll
  for (int c = 0; c < 4; c++){
    float bias = B2[j0 + cg + c * 16];
#pragma unroll
    for (int t = 0; t < 4; t++) acc[t][c] = bias;
  }
#pragma unroll 4
  for (int k4 = 0; k4 < 16; k4++){
    float4 lv[4];
#pragma unroll
    for (int t = 0; t < 4; t++)
      lv[t] = *(const float4*)(ntp + t * 64 + k4 * 4);
    float4 wv[4];
#pragma unroll
    for (int c = 0; c < 4; c++)
      wv[c] = *(const float4*)&wL[(cg + c * 16) * 68 + k4 * 4];
#pragma unroll
    for (int t = 0; t < 4; t++)
#pragma unroll
      for (int c = 0; c < 4; c++){
        acc[t][c] = fmaf(lv[t].x, wv[c].x, acc[t][c]);
        acc[t][c] = fmaf(lv[t].y, wv[c].y, acc[t][c]);
        acc[t][c] = fmaf(lv[t].z, wv[c].z, acc[t][c]);
        acc[t][c] = fmaf(lv[t].w, wv[c].w, acc[t][c]);
      }
  }
  if (j0 < 128){
    // 3 boundary tokens (zero at batch start)
    int isStart = ((t0 & 4095) == 0);
    if (tid < 192){
      int e = tid >> 6, col = tid & 63;
      float v = 0.f;
      if (!isStart){
        const float* np = NT + (size_t)(t0 - 3 + e) * 64;
        float a2 = B2[j0 + col];
#pragma unroll 4
        for (int k = 0; k < 64; k += 4){
          float4 nv = *(const float4*)(np + k);
          float4 wv = *(const float4*)&wL[col * 68 + k];
          a2 = fmaf(nv.x, wv.x, fmaf(nv.y, wv.y, fmaf(nv.z, wv.z, fmaf(nv.w, wv.w, a2))));
        }
        v = a2;
      }
      xcs[e * 68 + col] = v;
    }
#pragma unroll
    for (int t = 0; t < 4; t++)
#pragma unroll
      for (int c = 0; c < 4; c++)
        xcs[(3 + tq * 4 + t) * 68 + cg + c * 16] = acc[t][c];
    __syncthreads();
#pragma unroll
    for (int c = 0; c < 4; c++){
      int lc = cg + c * 16;
      int ch = j0 + lc;
      float4 wv = *(const float4*)(cw + ch * 4);
      float bias = cb[ch];
#pragma unroll
      for (int t = 0; t < 4; t++){
        int row = 3 + tq * 4 + t;
        float a = bias;
        a = fmaf(wv.w, xcs[row * 68 + lc], a);
        a = fmaf(wv.z, xcs[(row - 1) * 68 + lc], a);
        a = fmaf(wv.y, xcs[(row - 2) * 68 + lc], a);
        a = fmaf(wv.x, xcs[(row - 3) * 68 + lc], a);
        size_t tg = t0 + tq * 4 + t;
        U[tg * 128 + ch] = a * sigmoidf_(a);
      }
    }
  } else {
#pragma unroll
    for (int t = 0; t < 4; t++){
      size_t tg = t0 + tq * 4 + t;
#pragma unroll
      for (int c = 0; c < 4; c++)
        Z[tg * 128 + (j0 - 128) + cg + c * 16] = acc[t][c];
    }
  }
}

// ================= chunked parallel scan (4 states/thread, 32-token chunks) =================
// grid 2048 = 2m x 4b x 128chunk x 2cg. dt shared across q-lanes via shfl.
// x_proj FUSED: each block computes its chunk's dbl (36 outs) from the full-U LDS stage
// (exact xprojdt fmaf order -> bit-identical), stores transposed in LDS for the scan's
// B/dtr reads, and the cg==0 block writes DBL to global for scanC.
// FAST PATH: Alog = log(1..16) broadcast -> A[s] = -(s+1) exactly ->
// dA[s] = exp(-dt)^(s+1): one exp + power chain. Runtime-guarded with exp2 fallback.
__global__ __launch_bounds__(256) void k_scanA(
    float* __restrict__ DBL0, const float* __restrict__ U0, const float* __restrict__ AL0,
    const float* __restrict__ DTW0, const float* __restrict__ DTB0, const float* __restrict__ XW0,
    float* __restrict__ DBL1, const float* __restrict__ U1, const float* __restrict__ AL1,
    const float* __restrict__ DTW1, const float* __restrict__ DTB1, const float* __restrict__ XW1,
    float* __restrict__ HF, float* __restrict__ AP)
{
  __shared__ float su[32 * 132];     // full 128-ch chunk, stride 132
  __shared__ float sdblT[36 * 36];   // [out 36][token 32] (pad 36)
  __shared__ float sdtr[128];        // [token][4] for the dt dot
  int bid = blockIdx.x;
  int cg = bid & 1;
  int c  = (bid >> 1) & 127;
  int b  = (bid >> 8) & 3;
  int m  = bid >> 10;
  float* DBLp = m ? DBL1 : DBL0;
  const float* Up   = m ? U1   : U0;
  const float* ALp  = m ? AL1  : AL0;
  const float* DTWp = m ? DTW1 : DTW0;
  const float* DTBp = m ? DTB1 : DTB0;
  const float* XWp  = m ? XW1  : XW0;
  int tid = threadIdx.x;
  int lane = tid & 63, w = tid >> 6;
  int lcol = lane & 15, q = lane >> 4;
  int chL = w * 16 + lcol;
  int n = cg * 64 + chL;
  size_t base = (size_t)b * 4096 + c * 32;
  // stage full U chunk (32 x 128)
  for (int i = tid; i < 4096; i += 256){
    int ch = i & 127, l = i >> 7;
    su[l * 132 + ch] = Up[(base + l) * 128 + ch];
  }
  const float LOG2E = 1.4426950408889634f;
  float A1[4];
  bool fastp = true;
#pragma unroll
  for (int j = 0; j < 4; j++){
    A1[j] = -__expf(ALp[n * 16 + q * 4 + j]) * LOG2E;
    float expe = -(float)(q * 4 + j + 1) * LOG2E;
    fastp = fastp && (fabsf(A1[j] - expe) <= 1e-3f);
  }
  float4 wdt = *(const float4*)(DTWp + n * 4);
  float bdt = DTBp[n];
  __syncthreads();
  // x_proj for this chunk: 4 threads/token x 9 outs (exact xprojdt order)
  if (tid < 128){
    int slot = tid >> 2, jq = tid & 3;
    const float* sup = &su[slot * 132];
    float accA[9];
#pragma unroll
    for (int jj = 0; jj < 9; jj++) accA[jj] = 0.f;
    for (int k4 = 0; k4 < 32; k4++){
      float4 uA = *(const float4*)(sup + k4 * 4);
#pragma unroll
      for (int jj = 0; jj < 9; jj++){
        float4 wv = *(const float4*)&XWp[(size_t)(jq * 9 + jj) * 128 + k4 * 4];
        accA[jj] = fmaf(wv.x, uA.x, fmaf(wv.y, uA.y, fmaf(wv.z, uA.z, fmaf(wv.w, uA.w, accA[jj]))));
      }
    }
#pragma unroll
    for (int jj = 0; jj < 9; jj++){
      sdblT[(jq * 9 + jj) * 36 + slot] = accA[jj];
      if (cg == 0) DBLp[(base + slot) * 36 + jq * 9 + jj] = accA[jj];
    }
    if (jq == 0){
#pragma unroll
      for (int jj = 0; jj < 4; jj++) sdtr[slot * 4 + jj] = accA[jj];
    }
  }
  __syncthreads();
  float h[4] = {0.f, 0.f, 0.f, 0.f};
  float ap[4] = {1.f, 1.f, 1.f, 1.f};
#pragma unroll
  for (int l4 = 0; l4 < 8; l4++){
    int lq = l4 * 4 + q;
    float4 dq = *(const float4*)&sdtr[lq * 4];
    float xq = bdt;
    xq = fmaf(wdt.x, dq.x, xq); xq = fmaf(wdt.y, dq.y, xq);
    xq = fmaf(wdt.z, dq.z, xq); xq = fmaf(wdt.w, dq.w, xq);
    float dtq = softplus_(xq);
    float rq = __expf(-dtq);
    float dts[4], rs[4];
    dts[0] = __shfl(dtq, lcol);       rs[0] = __shfl(rq, lcol);
    dts[1] = __shfl(dtq, lcol + 16);  rs[1] = __shfl(rq, lcol + 16);
    dts[2] = __shfl(dtq, lcol + 32);  rs[2] = __shfl(rq, lcol + 32);
    dts[3] = __shfl(dtq, lcol + 48);  rs[3] = __shfl(rq, lcol + 48);
    float4 Bv[4];
#pragma unroll
    for (int j = 0; j < 4; j++) Bv[j] = *(const float4*)&sdblT[(4 + q * 4 + j) * 36 + l4 * 4];
    if (fastp){
#pragma unroll
      for (int jj = 0; jj < 4; jj++){
        int l = l4 * 4 + jj;
        float dt = dts[jj], r = rs[jj];
        float u  = su[l * 132 + n];
        float dtu = dt * u;
        float r2 = r * r, r4 = r2 * r2;
        float r8 = r4 * r4;
        float p0 = (q == 0) ? r : (q == 1) ? r4 * r : (q == 2) ? r8 * r : (r8 * r4) * r;
        float a0 = p0, a1 = a0 * r, a2 = a1 * r, a3 = a2 * r;
        h[0] = fmaf(a0, h[0], dtu * (&Bv[0].x)[jj]); ap[0] *= a0;
        h[1] = fmaf(a1, h[1], dtu * (&Bv[1].x)[jj]); ap[1] *= a1;
        h[2] = fmaf(a2, h[2], dtu * (&Bv[2].x)[jj]); ap[2] *= a2;
        h[3] = fmaf(a3, h[3], dtu * (&Bv[3].x)[jj]); ap[3] *= a3;
      }
    } else {
#pragma unroll
      for (int jj = 0; jj < 4; jj++){
        int l = l4 * 4 + jj;
        float dt = dts[jj];
        float u  = su[l * 132 + n];
        float dtu = dt * u;
#pragma unroll
        for (int j = 0; j < 4; j++){
          float a = exp2f(dt * A1[j]);
          h[j] = fmaf(a, h[j], dtu * (&Bv[j].x)[jj]);
          ap[j] *= a;
        }
      }
    }
  }
  size_t o = ((size_t)((m * 4 + b) * 128 + c)) * 2048 + n * 16 + q * 4;
  *(float4*)&HF[o] = make_float4(h[0], h[1], h[2], h[3]);
  *(float4*)&AP[o] = make_float4(ap[0], ap[1], ap[2], ap[3]);
}

// scanB: affine chunk-combine h <- a*h + f, parallelized 8 lanes/row via shfl affine scan.
__global__ __launch_bounds__(256) void k_scanB(
    const float* __restrict__ HF, const float* __restrict__ AP, float* __restrict__ HIN)
{
  int gid = blockIdx.x * 256 + threadIdx.x;
  int r = gid >> 3;          // row 0..16383 = (m*4+b)*2048 + (n*16+s)
  int seg = gid & 7;         // 16-chunk segment
  int q = r >> 11;
  int p = r & 2047;
  size_t base = (size_t)q * 128 * 2048 + p + (size_t)seg * 16 * 2048;
  float a[16], f[16];
#pragma unroll
  for (int c8 = 0; c8 < 2; c8++){
#pragma unroll
    for (int j = 0; j < 8; j++){
      size_t o = base + (size_t)(c8 * 8 + j) * 2048;
      a[c8 * 8 + j] = AP[o];
      f[c8 * 8 + j] = HF[o];
    }
  }
  float A = 1.f, F = 0.f;
#pragma unroll
  for (int j = 0; j < 16; j++){ F = fmaf(a[j], F, f[j]); A *= a[j]; }
#pragma unroll
  for (int d = 1; d < 8; d <<= 1){
    float Au = __shfl_up(A, d, 8);
    float Fu = __shfl_up(F, d, 8);
    if (seg >= d){ F = fmaf(A, Fu, F); A = A * Au; }
  }
  float hin = __shfl_up(F, 1, 8);
  float h = (seg == 0) ? 0.f : hin;
#pragma unroll
  for (int j = 0; j < 16; j++){
    size_t o = base + (size_t)j * 2048;
    HIN[o] = h;
    h = fmaf(a[j], h, f[j]);
  }
}

__global__ __launch_bounds__(256) void k_scanC(
    const float* __restrict__ DBL0, const float* __restrict__ U0, const float* __restrict__ AL0,
    const float* __restrict__ DTW0, const float* __restrict__ DTB0,
    const float* __restrict__ D0, float* __restrict__ Y0,
    const float* __restrict__ DBL1, const float* __restrict__ U1, const float* __restrict__ AL1,
    const float* __restrict__ DTW1, const float* __restrict__ DTB1,
    const float* __restrict__ D1, float* __restrict__ Y1,
    const float* __restrict__ HIN)
{
  __shared__ float su[32 * 65], sB[16 * 36], sC[16 * 36], sdtr[128];
  int bid = blockIdx.x;
  int cg = bid & 1;
  int c  = (bid >> 1) & 127;
  int b  = (bid >> 8) & 3;
  int m  = bid >> 10;
  const float* DBLp = m ? DBL1 : DBL0;
  const float* Up   = m ? U1   : U0;
  const float* ALp  = m ? AL1  : AL0;
  const float* DTWp = m ? DTW1 : DTW0;
  const float* DTBp = m ? DTB1 : DTB0;
  const float* Dp   = m ? D1   : D0;
  float*       Yp   = m ? Y1   : Y0;
  int tid = threadIdx.x;
  int lane = tid & 63, w = tid >> 6;
  int lcol = lane & 15, q = lane >> 4;
  int chL = w * 16 + lcol;
  int n = cg * 64 + chL;
  size_t base = (size_t)b * 4096 + c * 32;
  for (int i = tid; i < 2048; i += 256){
    int ch = i & 63, l = i >> 6;
    su[l * 65 + ch] = Up[(base + l) * 128 + cg * 64 + ch];
  }
  for (int i = tid; i < 512; i += 256){
    int s = i & 15, l = i >> 4;
    size_t ob = (base + l) * 36;
    sB[s * 36 + l] = DBLp[ob + 4 + s];
    sC[s * 36 + l] = DBLp[ob + 20 + s];
  }
  if (tid < 128){
    int l = tid >> 2, jj = tid & 3;
    sdtr[tid] = DBLp[(base + l) * 36 + jj];
  }
  const float LOG2E = 1.4426950408889634f;
  float A1[4];
  bool fastp = true;
#pragma unroll
  for (int j = 0; j < 4; j++){
    A1[j] = -__expf(ALp[n * 16 + q * 4 + j]) * LOG2E;
    float expe = -(float)(q * 4 + j + 1) * LOG2E;
    fastp = fastp && (fabsf(A1[j] - expe) <= 1e-3f);
  }
  float4 wdt = *(const float4*)(DTWp + n * 4);
  float bdt = DTBp[n];
  float Dn = Dp[n];
  float4 hv = *(const float4*)&HIN[((size_t)((m * 4 + b) * 128 + c)) * 2048 + n * 16 + q * 4];
  float h[4] = {hv.x, hv.y, hv.z, hv.w};
  __syncthreads();
#pragma unroll
  for (int l4 = 0; l4 < 8; l4++){
    int lq = l4 * 4 + q;
    float4 dq = *(const float4*)&sdtr[lq * 4];
    float xq = bdt;
    xq = fmaf(wdt.x, dq.x, xq); xq = fmaf(wdt.y, dq.y, xq);
    xq = fmaf(wdt.z, dq.z, xq); xq = fmaf(wdt.w, dq.w, xq);
    float dtq = softplus_(xq);
    float rq = __expf(-dtq);
    float dts[4], rs[4];
    dts[0] = __shfl(dtq, lcol);       rs[0] = __shfl(rq, lcol);
    dts[1] = __shfl(dtq, lcol + 16);  rs[1] = __shfl(rq, lcol + 16);
    dts[2] = __shfl(dtq, lcol + 32);  rs[2] = __shfl(rq, lcol + 32);
    dts[3] = __shfl(dtq, lcol + 48);  rs[3] = __shfl(rq, lcol + 48);
    float4 Bv[4], Cv[4];
#pragma unroll
    for (int j = 0; j < 4; j++){
      Bv[j] = *(const float4*)&sB[(q * 4 + j) * 36 + l4 * 4];
      Cv[j] = *(const float4*)&sC[(q * 4 + j) * 36 + l4 * 4];
    }
    if (fastp){
#pragma unroll
      for (int jj = 0; jj < 4; jj++){
        int l = l4 * 4 + jj;
        float dt = dts[jj], r = rs[jj];
        float u  = su[l * 65 + chL];
        float dtu = dt * u;
        float r2 = r * r, r4 = r2 * r2;
        float r8 = r4 * r4;
        float p0 = (q == 0) ? r : (q == 1) ? r4 * r : (q == 2) ? r8 * r : (r8 * r4) * r;
        float a0 = p0, a1 = a0 * r, a2 = a1 * r, a3 = a2 * r;
        float p = 0.f;
        h[0] = fmaf(a0, h[0], dtu * (&Bv[0].x)[jj]); p = fmaf(h[0], (&Cv[0].x)[jj], p);
        h[1] = fmaf(a1, h[1], dtu * (&Bv[1].x)[jj]); p = fmaf(h[1], (&Cv[1].x)[jj], p);
        h[2] = fmaf(a2, h[2], dtu * (&Bv[2].x)[jj]); p = fmaf(h[2], (&Cv[2].x)[jj], p);
        h[3] = fmaf(a3, h[3], dtu * (&Bv[3].x)[jj]); p = fmaf(h[3], (&Cv[3].x)[jj], p);
        p += __shfl_xor(p, 16);
        p += __shfl_xor(p, 32);
        if (q == 0)
          Yp[(base + l) * 128 + n] = fmaf(u, Dn, p);
      }
    } else {
#pragma unroll
      for (int jj = 0; jj < 4; jj++){
        int l = l4 * 4 + jj;
        float dt = dts[jj];
        float u  = su[l * 65 + chL];
        float dtu = dt * u;
        float p = 0.f;
#pragma unroll
        for (int j = 0; j < 4; j++){
          float a = exp2f(dt * A1[j]);
          h[j] = fmaf(a, h[j], dtu * (&Bv[j].x)[jj]);
          p = fmaf(h[j], (&Cv[j].x)[jj], p);
        }
        p += __shfl_xor(p, 16);
        p += __shfl_xor(p, 32);
        if (q == 0)
          Yp[(base + l) * 128 + n] = fmaf(u, Dn, p);
      }
    }
  }
}

// ---------------- out_proj (both mambas): ((Y)*silu(Z)) @ W^T + softmax partials for m=1 ----------------
__global__ __launch_bounds__(256) void k_outproj(
    const float* __restrict__ Y0, const float* __restrict__ Zg0,
    const float* __restrict__ W0, float* __restrict__ OUT0,
    const float* __restrict__ Y1, const float* __restrict__ Zg1,
    const float* __restrict__ W1, float* __restrict__ OUT1,
    float* __restrict__ P)
{
  __shared__ float yl[16 * 128];
  __shared__ float wT[128 * 65];
  __shared__ float rM[256], rS[256];
  int m = blockIdx.y;
  const float* Y  = m ? Y1  : Y0;
  const float* Zg = m ? Zg1 : Zg0;
  const float* W  = m ? W1  : W0;
  float* OUT = m ? OUT1 : OUT0;
  int tid = threadIdx.x;
  size_t t0 = (size_t)blockIdx.x * 16;
  for (int i = tid; i < 2048; i += 256){
    float z = Zg[t0 * 128 + i];
    yl[i] = Y[t0 * 128 + i] * (z * sigmoidf_(z));
  }
  for (int i = tid; i < 8192; i += 256){
    int k = i & 127, j = i >> 7;
    wT[k * 65 + j] = W[j * 128 + k];
  }
  __syncthreads();
  int j = tid & 63;
  int tg = tid >> 6;
  float acc[4] = {0.f, 0.f, 0.f, 0.f};
  for (int k = 0; k < 128; k += 4){
    float w0 = wT[k * 65 + j], w1 = wT[(k+1) * 65 + j];
    float w2 = wT[(k+2) * 65 + j], w3 = wT[(k+3) * 65 + j];
#pragma unroll
    for (int t = 0; t < 4; t++){
      float4 yv = *(const float4*)&yl[(tg * 4 + t) * 128 + k];
      acc[t] = fmaf(w0, yv.x, fmaf(w1, yv.y, fmaf(w2, yv.z, fmaf(w3, yv.w, acc[t]))));
    }
  }
#pragma unroll
  for (int t = 0; t < 4; t++)
    OUT[(t0 + tg * 4 + t) * 64 + j] = acc[t];
  if (m == 1){
    float mx = fmaxf(fmaxf(acc[0], acc[1]), fmaxf(acc[2], acc[3]));
    float sm = __expf(acc[0] - mx) + __expf(acc[1] - mx) + __expf(acc[2] - mx) + __expf(acc[3] - mx);
    rM[tid] = mx; rS[tid] = sm;
    __syncthreads();
    if (tid < 64){
      float M = rM[tid], S = rS[tid];
      for (int p2 = 1; p2 < 4; p2++){
        float m2 = rM[p2 * 64 + tid], s2 = rS[p2 * 64 + tid];
        float Mn = fmaxf(M, m2);
        S = S * __expf(M - Mn) + s2 * __expf(m2 - Mn);
        M = Mn;
      }
      P[((size_t)blockIdx.x * 64 + tid) * 2] = M;
      P[((size_t)blockIdx.x * 64 + tid) * 2 + 1] = S;
    }
  }
}

// ---------------- combine (+softmax finalize) + transpose to (b,c,64,64) ----------------
// P holds 256 partials per (b, j) (one per 16-token outproj block).
__global__ void k_combine(const float* __restrict__ T, const float* __restrict__ MAIN,
                          const float* __restrict__ G, const float* __restrict__ P,
                          float* __restrict__ FEAT){
  int bid = blockIdx.x;
  int b = bid >> 6, row = bid & 63;
  int tid = threadIdx.x;
  __shared__ float tile[64 * 65];
  __shared__ float sM[256], sS[256], Mv[64], iSv[64];
  {
    int j2 = tid & 63, part = tid >> 6;
    float M = -3.4e38f, S = 0.f;
    for (int i = 0; i < 64; i++){
      int pb = part + i * 4;               // 0..255
      int idx = ((b * 256 + pb) * 64 + j2) * 2;
      float m2 = P[idx], s2 = P[idx + 1];
      float Mn = fmaxf(M, m2);
      S = S * __expf(M - Mn) + s2 * __expf(m2 - Mn);
      M = Mn;
    }
    sM[tid] = M; sS[tid] = S;
  }
  __syncthreads();
  if (tid < 64){
    float M = sM[tid], S = sS[tid];
    for (int p = 1; p < 4; p++){
      float m2 = sM[p * 64 + tid], s2 = sS[p * 64 + tid];
      float Mn = fmaxf(M, m2);
      S = S * __expf(M - Mn) + s2 * __expf(m2 - Mn);
      M = Mn;
    }
    Mv[tid] = M; iSv[tid] = 1.f / S;
  }
  __syncthreads();
  int j = tid & 63, ls = tid >> 6;
  float M = Mv[j], invS = iSv[j];
  size_t lbase = (size_t)b * 4096 + row * 64;
  for (int i = 0; i < 16; i++){
    int col = ls + i * 4;
    size_t off = (lbase + col) * 64 + j;
    float g = __expf(G[off] - M) * invS;
    tile[col * 65 + j] = T[off] + g * MAIN[off];
  }
  __syncthreads();
  int colw = tid & 63, jr = tid >> 6;
  for (int jj = jr; jj < 64; jj += 4)
    FEAT[(((size_t)b * 64 + jj) * 64 + row) * 64 + colw] = tile[colw * 65 + jj];
}

// ---------------- host launcher ----------------
extern "C" void kernel_launch(void* const* d_in, const int* in_sizes, int n_in,
                              void* d_out, int out_size, void* d_ws, size_t ws_size,
                              hipStream_t stream) {
  // workspace layout (float offsets)
  const size_t P1A = 0, P1B = 4326400;
  const size_t MB0 = 0, MB1 = 10027008;
  const size_t O_LN = 0, O_XC = 1048576, O_Z = 3145728, O_U = 5242880,
               O_DBL = 9437184;
  const size_t TOK = 20054016, OUT0 = 21102592, OUT1 = 22151168;
  const size_t FEAT = 23208448;
  const size_t P3A = 4194304, P3B = 8520704;
  const size_t WSET = 19000000;         // 8 x 18432 floats: cb1h,cb1l,cb2h,cb2l,sw1h,sw1l,sw2h,sw2l
  const size_t PADN = 2163200;
  const size_t SMP = 0;                 // softmax partials: 1024 x 64 x 2 floats
  const size_t W2_0 = 21102592, B2_0 = 21118976, W2_1 = 21119232, B2_1 = 21135616;
  const size_t TOTAL = 24257024;
  if (ws_size < TOTAL * 4) return;

  float* ws = (float*)d_ws;
  const float* X   = (const float*)d_in[0];
  const float* CB1 = (const float*)d_in[1];
  const float* CB2 = (const float*)d_in[2];
  const float* SW1 = (const float*)d_in[3];
  const float* SW2 = (const float*)d_in[4];
  const float* LNW[2] = { (const float*)d_in[5], (const float*)d_in[7] };
  const float* LNB[2] = { (const float*)d_in[6], (const float*)d_in[8] };
  const float *INW[2], *CW[2], *CBb[2], *XPW[2], *DTW[2], *DTB[2], *AL[2], *DD[2], *OW[2];
  for (int m = 0; m < 2; m++){
    int p = 9 + m * 9;
    INW[m] = (const float*)d_in[p + 0];
    CW[m]  = (const float*)d_in[p + 1];
    CBb[m] = (const float*)d_in[p + 2];
    XPW[m] = (const float*)d_in[p + 3];
    DTW[m] = (const float*)d_in[p + 4];
    DTB[m] = (const float*)d_in[p + 5];
    AL[m]  = (const float*)d_in[p + 6];
    DD[m]  = (const float*)d_in[p + 7];
    OW[m]  = (const float*)d_in[p + 8];
  }

  u16* wset[8];
  for (int k = 0; k < 8; k++) wset[k] = (u16*)(ws + WSET + (size_t)k * 18432);

  u16* p1ah = (u16*)(ws + P1A); u16* p1al = p1ah + PADN * 2;
  u16* p1bh = (u16*)(ws + P1B); u16* p1bl = p1bh + PADN * 2;
  u16* p3ah = (u16*)(ws + P3A); u16* p3al = p3ah + PADN * 2;
  u16* p3bh = (u16*)(ws + P3B); u16* p3bl = p3bh + PADN * 2;

  // ---- setup (weight swizzles + LN fold) + prep of X, one launch ----
  k_setup<<<1097, 256, 0, stream>>>(CB1, wset[0], wset[1], CB2, wset[2], wset[3],
                                    SW1, wset[4], wset[5], SW2, wset[6], wset[7],
                                    INW[0], LNW[0], LNB[0], ws + W2_0, ws + B2_0,
                                    INW[1], LNW[1], LNB[1], ws + W2_1, ws + B2_1,
                                    X, p1ah, p1al, p1bh, p1bl);

  // ---- phase 1: conv block (MFMA) + fused tokenize/LN ----
  k_convm<<<dim3(8, 16, 4), 256, 0, stream>>>(p1ah, p1al, wset[0], wset[1], nullptr,
                                              p1bh, p1bl, nullptr, nullptr, nullptr, 0);
  k_convm<<<dim3(8, 16, 4), 256, 0, stream>>>(p1bh, p1bl, wset[2], wset[3], X,
                                              nullptr, nullptr, nullptr,
                                              ws + TOK, ws + MB0 + O_LN, 2);

  // ---- phase 2: mamba x2 (x_proj fused into scanA) ----
  k_inprojdw<<<dim3(256, 4, 2), 256, 0, stream>>>(
      ws + MB0 + O_LN,
      ws + W2_0, ws + B2_0, ws + MB0 + O_U, ws + MB0 + O_Z, CW[0], CBb[0],
      ws + W2_1, ws + B2_1, ws + MB1 + O_U, ws + MB1 + O_Z, CW[1], CBb[1]);

  // scan buffers (2M floats each, 32-token chunks -> 1024 chunk-rows x 2048):
  // HF -> MB0+O_XC (overwritten by Y0 in scanC, after scanB consumed it)
  // AP -> MB1+O_XC (overwritten by Y1 in scanC, after scanB consumed it)
  // HIN -> OUT1..FEAT span (dead until k_outproj / k_combine)
  float* HF  = ws + MB0 + O_XC;
  float* AP  = ws + MB1 + O_XC;
  float* HIN = ws + OUT1;

  k_scanA<<<2048, 256, 0, stream>>>(
      ws + MB0 + O_DBL, ws + MB0 + O_U, AL[0], DTW[0], DTB[0], XPW[0],
      ws + MB1 + O_DBL, ws + MB1 + O_U, AL[1], DTW[1], DTB[1], XPW[1],
      HF, AP);
  k_scanB<<<512, 256, 0, stream>>>(HF, AP, HIN);
  k_scanC<<<2048, 256, 0, stream>>>(
      ws + MB0 + O_DBL, ws + MB0 + O_U, AL[0], DTW[0], DTB[0], DD[0], ws + MB0 + O_XC,
      ws + MB1 + O_DBL, ws + MB1 + O_U, AL[1], DTW[1], DTB[1], DD[1], ws + MB1 + O_XC,
      HIN);

  k_outproj<<<dim3(1024, 2), 256, 0, stream>>>(
      ws + MB0 + O_XC, ws + MB0 + O_Z, OW[0], ws + OUT0,
      ws + MB1 + O_XC, ws + MB1 + O_Z, OW[1], ws + OUT1,
      ws + SMP);

  k_combine<<<256, 256, 0, stream>>>(ws + TOK, ws + OUT0, ws + OUT1, ws + SMP, ws + FEAT);

  // ---- phase 3: fused upsample+prep + conv block (MFMA) ----
  k_prepup<<<dim3(130, 4), 256, 0, stream>>>(ws + FEAT, p3ah, p3al, p3bh, p3bl);
  k_convm<<<dim3(8, 16, 4), 256, 0, stream>>>(p3ah, p3al, wset[4], wset[5], nullptr,
                                              p3bh, p3bl, nullptr, nullptr, nullptr, 0);
  k_convm<<<dim3(8, 16, 4), 256, 0, stream>>>(p3bh, p3bl, wset[6], wset[7], nullptr,
                                              nullptr, nullptr, (float*)d_out,
                                              nullptr, nullptr, 1);
}

// Round 13
// 349.387 us; speedup vs baseline: 1.3174x; 1.3174x over previous
//
#include <hip/hip_runtime.h>

typedef unsigned int u32;
typedef unsigned short u16;
typedef __attribute__((ext_vector_type(8))) short short8;
typedef __attribute__((ext_vector_type(4))) float f32x4;

__device__ __forceinline__ float sigmoidf_(float x){
  return 1.f / (1.f + __expf(-x));
}
__device__ __forceinline__ u16 f2bf(float f){
  union { float f; u32 i; } v; v.f = f;
  u32 r = v.i + 0x7fffu + ((v.i >> 16) & 1u);
  return (u16)(r >> 16);
}
__device__ __forceinline__ float bf2f(u32 u){
  union { float f; u32 i; } v; v.i = (u & 0xffffu) << 16; return v.f;
}
// fast softplus: max(x,0) + log(1+exp(-|x|)); abs err < 6e-8 vs log1pf
__device__ __forceinline__ float softplus_(float x){
  return fmaxf(x, 0.f) + __logf(1.f + __expf(-fabsf(x)));
}

// ---------------- setup (swizzle 4 weight sets + LN fold) + prep (pad X) in ONE launch ----------------
// blocks [0,577): weight swizzle + fold; blocks [577,1097): prep rows (independent work).
__global__ __launch_bounds__(256) void k_setup(
    const float* __restrict__ w0, u16* __restrict__ h0, u16* __restrict__ l0,
    const float* __restrict__ w1, u16* __restrict__ h1, u16* __restrict__ l1,
    const float* __restrict__ w2, u16* __restrict__ h2, u16* __restrict__ l2,
    const float* __restrict__ w3, u16* __restrict__ h3, u16* __restrict__ l3,
    const float* __restrict__ Wa, const float* __restrict__ lnwa, const float* __restrict__ lnba,
    float* __restrict__ W2a, float* __restrict__ B2a,
    const float* __restrict__ Wb, const float* __restrict__ lnwb, const float* __restrict__ lnbb,
    float* __restrict__ W2b, float* __restrict__ B2b,
    const float* __restrict__ src, u16* __restrict__ PH, u16* __restrict__ PL,
    u16* __restrict__ BPH, u16* __restrict__ BPL)
{
  __shared__ float ld[64 * 129];
  int bx = blockIdx.x;
  int tid = threadIdx.x;
  if (bx < 577){
    int gidx = bx * 256 + tid;   // -> 147712
    if (gidx < 147456){
      int set = gidx / 36864;
      int idx = gidx - set * 36864;
      const float* w; u16* WH; u16* WL;
      if (set == 0){ w = w0; WH = h0; WL = l0; }
      else if (set == 1){ w = w1; WH = h1; WL = l1; }
      else if (set == 2){ w = w2; WH = h2; WL = l2; }
      else { w = w3; WH = h3; WL = l3; }
      int j    = idx & 7;
      int lane = (idx >> 3) & 63;
      int nt   = (idx >> 9) & 3;
      int kc   = (idx >> 11) & 1;
      int t    = idx >> 12;           // 0..8
      int ic = kc * 32 + ((lane >> 4) & 3) * 8 + j;
      int oc = nt * 16 + (lane & 15);
      float v = w[(oc * 64 + ic) * 9 + t];
      u16 h = f2bf(v);
      u16 l = f2bf(v - bf2f(h));
      WH[idx] = h; WL[idx] = l;
    } else {
      int i = gidx - 147456;          // 128 fold rows
      if (i >= 128) return;
      int m = i >> 6, j = i & 63;
      const float* W   = m ? Wb   : Wa;
      const float* lnw = m ? lnwb : lnwa;
      const float* lnb = m ? lnbb : lnba;
      float* W2 = m ? W2b : W2a;
      float* B2 = m ? B2b : B2a;
      float bias = 0.f;
#pragma unroll
      for (int k4 = 0; k4 < 16; k4++){
        float4 wv = *(const float4*)&W[j * 64 + k4 * 4];
        float4 gw = *(const float4*)&lnw[k4 * 4];
        float4 gb = *(const float4*)&lnb[k4 * 4];
        W2[j * 64 + k4 * 4 + 0] = wv.x * gw.x;
        W2[j * 64 + k4 * 4 + 1] = wv.y * gw.y;
        W2[j * 64 + k4 * 4 + 2] = wv.z * gw.z;
        W2[j * 64 + k4 * 4 + 3] = wv.w * gw.w;
        bias = fmaf(wv.x, gb.x, bias);
        bias = fmaf(wv.y, gb.y, bias);
        bias = fmaf(wv.z, gb.z, bias);
        bias = fmaf(wv.w, gb.w, bias);
      }
      B2[j] = bias;
    }
  } else {
    // prep: NCHW fp32 -> padded NHWC bf16 hi/lo (+ zero borders of stage-2 pad)
    int bid2 = bx - 577;
    int yp = bid2 % 130;
    int b  = bid2 / 130;
    int ys = yp - 1;
    if (yp == 0 || yp == 129){
      for (int i = tid; i < 130 * 64; i += 256){
        int x = i >> 6, c = i & 63;
        size_t o = (((size_t)b * 130 + yp) * 130 + x) * 64 + c;
        BPH[o] = 0; BPL[o] = 0;
      }
    } else {
      for (int i = tid; i < 128; i += 256){
        int x = (i >= 64) ? 129 : 0, c = i & 63;
        size_t o = (((size_t)b * 130 + yp) * 130 + x) * 64 + c;
        BPH[o] = 0; BPL[o] = 0;
      }
    }
    if ((u32)ys < 128u){
      for (int i = tid; i < 8192; i += 256){
        int c = i >> 7, x = i & 127;
        ld[c * 129 + x] = src[((size_t)(b * 64 + c) * 128 + ys) * 128 + x];
      }
    }
    __syncthreads();
    for (int i = tid; i < 130 * 64; i += 256){
      int xp = i >> 6, c = i & 63;
      float v = 0.f;
      if ((u32)ys < 128u && (u32)(xp - 1) < 128u) v = ld[c * 129 + (xp - 1)];
      u16 h = f2bf(v);
      u16 l = f2bf(v - bf2f(h));
      size_t o = (((size_t)b * 130 + yp) * 130 + xp) * 64 + c;
      PH[o] = h; PL[o] = l;
    }
  }
}

// ---------------- prep with fused bilinear upsample 64->128 (+ zero borders of next pad) ----------------
// LDS stride padded to 65: read bank = (c + x) % 32 -> 2-way (free).
__global__ __launch_bounds__(256) void k_prepup(const float* __restrict__ FEAT,
                                                u16* __restrict__ PH, u16* __restrict__ PL,
                                                u16* __restrict__ BPH, u16* __restrict__ BPL){
  __shared__ float ld0[64 * 65], ld1[64 * 65];
  int yp = blockIdx.x;
  int b  = blockIdx.y;
  int ys = yp - 1;
  int tid = threadIdx.x;
  if (yp == 0 || yp == 129){
    for (int i = tid; i < 130 * 64; i += 256){
      int x = i >> 6, c = i & 63;
      size_t o = (((size_t)b * 130 + yp) * 130 + x) * 64 + c;
      BPH[o] = 0; BPL[o] = 0;
    }
  } else {
    for (int i = tid; i < 128; i += 256){
      int x = (i >= 64) ? 129 : 0, c = i & 63;
      size_t o = (((size_t)b * 130 + yp) * 130 + x) * 64 + c;
      BPH[o] = 0; BPL[o] = 0;
    }
  }
  float wy = 0.f;
  if ((u32)ys < 128u){
    float ay = 0.5f * ys - 0.25f;
    int fy = (int)floorf(ay); wy = ay - fy;
    int y0s = fy < 0 ? 0 : fy, y1s = fy + 1 > 63 ? 63 : fy + 1;
    for (int i = tid; i < 1024; i += 256){
      int c = i >> 4, x4 = (i & 15) * 4;
      float4 a0 = *(const float4*)&FEAT[((size_t)(b * 64 + c) * 64 + y0s) * 64 + x4];
      float4 a1 = *(const float4*)&FEAT[((size_t)(b * 64 + c) * 64 + y1s) * 64 + x4];
      ld0[c * 65 + x4 + 0] = a0.x; ld0[c * 65 + x4 + 1] = a0.y;
      ld0[c * 65 + x4 + 2] = a0.z; ld0[c * 65 + x4 + 3] = a0.w;
      ld1[c * 65 + x4 + 0] = a1.x; ld1[c * 65 + x4 + 1] = a1.y;
      ld1[c * 65 + x4 + 2] = a1.z; ld1[c * 65 + x4 + 3] = a1.w;
    }
  }
  __syncthreads();
  for (int i = tid; i < 130 * 64; i += 256){
    int xp = i >> 6, c = i & 63;
    float v = 0.f;
    int xs = xp - 1;
    if ((u32)ys < 128u && (u32)xs < 128u){
      float ax = 0.5f * xs - 0.25f;
      int fx = (int)floorf(ax); float wx = ax - fx;
      int x0s = fx < 0 ? 0 : fx, x1s = fx + 1 > 63 ? 63 : fx + 1;
      float v0 = (1.f - wx) * ld0[c * 65 + x0s] + wx * ld0[c * 65 + x1s];
      float v1 = (1.f - wx) * ld1[c * 65 + x0s] + wx * ld1[c * 65 + x1s];
      v = (1.f - wy) * v0 + wy * v1;
    }
    u16 h = f2bf(v);
    u16 l = f2bf(v - bf2f(h));
    size_t o = (((size_t)b * 130 + yp) * 130 + xp) * 64 + c;
    PH[o] = h; PL[o] = l;
  }
}

// ---------------- MFMA conv3x3 64->64 (16x8 px tile, 2 blocks/CU) ----------------
// grid (8,16,4): 16x8 px tile, 64 oc. block 256 = 4 waves; wave w = rows {2w,2w+1}.
// mode 0: relu -> padded bf16 h/l.  mode 1: fp32 NCHW (+resid).
// mode 2: (+resid) -> fused 2x2-avg tokenize + LN -> T, NT.
__global__ __launch_bounds__(256) void k_convm(
    const u16* __restrict__ PH, const u16* __restrict__ PL,
    const u16* __restrict__ WH, const u16* __restrict__ WL,
    const float* __restrict__ resid,
    u16* __restrict__ OBH, u16* __restrict__ OBL,
    float* __restrict__ OUTF, float* __restrict__ T, float* __restrict__ NT,
    int mode)
{
  __shared__ __align__(16) u32 smem[9024];   // stage 5760 | epi(+red) 9024
  u16* Ah_s = (u16*)smem;                    // 5760 u16: [10r][18c][32ic]
  u16* Al_s = Ah_s + 5760;
  int tid = threadIdx.x;
  int lane = tid & 63, w = tid >> 6;
  int quad = lane >> 4, lcol = lane & 15;
  int b = blockIdx.z, y0 = blockIdx.y * 8, x0 = blockIdx.x * 16;

  f32x4 acc[2][4];
#pragma unroll
  for (int mt = 0; mt < 2; mt++)
#pragma unroll
    for (int nt = 0; nt < 4; nt++)
      acc[mt][nt] = (f32x4){0.f, 0.f, 0.f, 0.f};

  for (int kc = 0; kc < 2; kc++){
    __syncthreads();
    for (int i = tid; i < 720; i += 256){
      int q = i & 3;
      int rc = i >> 2;
      int r = rc / 18, c = rc - r * 18;
      size_t so = (((size_t)b * 130 + y0 + r) * 130 + (x0 + c)) * 64 + kc * 32 + q * 8;
      int de = (r * 18 + c) * 32 + q * 8;
      *(uint4*)(Ah_s + de) = *(const uint4*)(PH + so);
      *(uint4*)(Al_s + de) = *(const uint4*)(PL + so);
    }
    __syncthreads();
#pragma unroll
    for (int t = 0; t < 9; t++){
      int dy = t / 3, dx = t - dy * 3;
      short8 bh[4], bl[4];
#pragma unroll
      for (int nt = 0; nt < 4; nt++){
        int o = ((t * 2 + kc) * 4 + nt) * 512 + lane * 8;
        bh[nt] = *(const short8*)(WH + o);
        bl[nt] = *(const short8*)(WL + o);
      }
      short8 ah[2], al[2];
#pragma unroll
      for (int mt = 0; mt < 2; mt++){
        int e = ((w * 2 + mt + dy) * 18 + (lcol + dx)) * 32 + quad * 8;
        ah[mt] = *(const short8*)(Ah_s + e);
        al[mt] = *(const short8*)(Al_s + e);
      }
#pragma unroll
      for (int mt = 0; mt < 2; mt++)
#pragma unroll
        for (int nt = 0; nt < 4; nt++){
          acc[mt][nt] = __builtin_amdgcn_mfma_f32_16x16x32_bf16(ah[mt], bh[nt], acc[mt][nt], 0, 0, 0);
          acc[mt][nt] = __builtin_amdgcn_mfma_f32_16x16x32_bf16(ah[mt], bl[nt], acc[mt][nt], 0, 0, 0);
          acc[mt][nt] = __builtin_amdgcn_mfma_f32_16x16x32_bf16(al[mt], bh[nt], acc[mt][nt], 0, 0, 0);
        }
    }
  }

  // epilogue. C-frag: col(lane&15)=oc-in-tile, row(quad*4+reg)=px-col.
  __syncthreads();
  if (mode == 0){
    u32* epi = smem;   // [px 128][oc 66]
#pragma unroll
    for (int mt = 0; mt < 2; mt++){
      int row = w * 2 + mt;
#pragma unroll
      for (int nt = 0; nt < 4; nt++){
#pragma unroll
        for (int reg = 0; reg < 4; reg++){
          float v = fmaxf(acc[mt][nt][reg], 0.f);
          u32 h = f2bf(v);
          u32 l = f2bf(v - bf2f(h));
          int ccol = quad * 4 + reg;
          int oc = nt * 16 + lcol;
          epi[(row * 16 + ccol) * 66 + oc] = h | (l << 16);
        }
      }
    }
    __syncthreads();
    for (int i = tid; i < 8192; i += 256){
      int px = i >> 6, oc = i & 63;
      int row = px >> 4, ccol = px & 15;
      u32 pk = epi[px * 66 + oc];
      size_t o = (((size_t)b * 130 + y0 + row + 1) * 130 + (x0 + ccol + 1)) * 64 + oc;
      OBH[o] = (u16)pk;
      OBL[o] = (u16)(pk >> 16);
    }
  } else {
    float* epi = (float*)smem;  // [oc 64][px 131]
#pragma unroll
    for (int mt = 0; mt < 2; mt++){
      int row = w * 2 + mt;
#pragma unroll
      for (int nt = 0; nt < 4; nt++){
#pragma unroll
        for (int reg = 0; reg < 4; reg++){
          int px = row * 16 + quad * 4 + reg;
          int oc = nt * 16 + lcol;
          epi[oc * 131 + px] = acc[mt][nt][reg];
        }
      }
    }
    __syncthreads();
    if (mode == 1){
      for (int i = tid; i < 8192; i += 256){
        int oc = i >> 7, px = i & 127;
        int row = px >> 4, c = px & 15;
        size_t o = (((size_t)b * 64 + oc) * 128 + y0 + row) * 128 + x0 + c;
        float v = epi[oc * 131 + px];
        if (resid) v += resid[o];
        OUTF[o] = v;
      }
    } else {
      // mode 2: add residual into LDS, then tokenize + LN
      for (int i = tid; i < 8192; i += 256){
        int oc = i >> 7, px = i & 127;
        int row = px >> 4, c = px & 15;
        size_t o = (((size_t)b * 64 + oc) * 128 + y0 + row) * 128 + x0 + c;
        epi[oc * 131 + px] += resid[o];
      }
      __syncthreads();
      float* redS  = (float*)smem + 8384;  // [32][9]
      float* redQ  = redS + 288;           // [32][9]
      float* stats = redQ + 288;           // [32][2]
      int token = tid & 31, cgrp = tid >> 5;
      int tr = token >> 3, tc = token & 7;
      float av[8]; float s = 0.f, q = 0.f;
      int p0 = (2 * tr) * 16 + 2 * tc;
#pragma unroll
      for (int j = 0; j < 8; j++){
        int c = cgrp * 8 + j;
        const float* ep = epi + c * 131;
        float v = 0.25f * (ep[p0] + ep[p0 + 1] + ep[p0 + 16] + ep[p0 + 17]);
        av[j] = v; s += v; q = fmaf(v, v, q);
      }
      redS[token * 9 + cgrp] = s;
      redQ[token * 9 + cgrp] = q;
      __syncthreads();
      if (tid < 32){
        float S = 0.f, Q = 0.f;
        for (int g = 0; g < 8; g++){ S += redS[tid * 9 + g]; Q += redQ[tid * 9 + g]; }
        float mu = S * (1.f / 64.f);
        float var = Q * (1.f / 64.f) - mu * mu;
        stats[tid * 2] = mu;
        stats[tid * 2 + 1] = rsqrtf(var + 1e-5f);
      }
      __syncthreads();
      float mu = stats[token * 2], inv = stats[token * 2 + 1];
      int l = (blockIdx.y * 4 + tr) * 64 + blockIdx.x * 8 + tc;
      size_t to = ((size_t)b * 4096 + l) * 64 + cgrp * 8;
#pragma unroll
      for (int j = 0; j < 8; j++){
        T[to + j] = av[j];
        NT[to + j] = (av[j] - mu) * inv;
      }
    }
  }
}

// ---------------- in_proj + fused dwconv/silu (both mambas) ----------------
// grid (256, 4, 2): x = 64-token tile, y = 64-col quarter (0,1 -> XC->U; 2,3 -> Z).
__global__ __launch_bounds__(256) void k_inprojdw(
    const float* __restrict__ NT,
    const float* __restrict__ W2a, const float* __restrict__ B2a,
    float* __restrict__ Ua, float* __restrict__ Za,
    const float* __restrict__ cwa, const float* __restrict__ cba,
    const float* __restrict__ W2b, const float* __restrict__ B2b,
    float* __restrict__ Ub, float* __restrict__ Zb,
    const float* __restrict__ cwb, const float* __restrict__ cbb)
{
  __shared__ float wL[64 * 68];
  __shared__ float xcs[67 * 68];
  int mz = blockIdx.z;
  const float* W2 = mz ? W2b : W2a;
  const float* B2 = mz ? B2b : B2a;
  float* U = mz ? Ub : Ua;
  float* Z  = mz ? Zb : Za;
  const float* cw = mz ? cwb : cwa;
  const float* cb = mz ? cbb : cba;
  int tid = threadIdx.x;
  int t0 = blockIdx.x * 64;
  int j0 = blockIdx.y * 64;
  for (int i = tid; i < 4096; i += 256){
    int jl = i >> 6, k = i & 63;
    wL[jl * 68 + k] = W2[(size_t)(j0 + jl) * 64 + k];
  }
  __syncthreads();
  int tq = tid >> 4, cg = tid & 15;
  const float* ntp = NT + (size_t)(t0 + tq * 4) * 64;
  float acc[4][4];
#pragma unroll
  for (int c = 0; c < 4; c++){
    float bias = B2[j0 + cg + c * 16];
#pragma unroll
    for (int t = 0; t < 4; t++) acc[t][c] = bias;
  }
#pragma unroll 4
  for (int k4 = 0; k4 < 16; k4++){
    float4 lv[4];
#pragma unroll
    for (int t = 0; t < 4; t++)
      lv[t] = *(const float4*)(ntp + t * 64 + k4 * 4);
    float4 wv[4];
#pragma unroll
    for (int c = 0; c < 4; c++)
      wv[c] = *(const float4*)&wL[(cg + c * 16) * 68 + k4 * 4];
#pragma unroll
    for (int t = 0; t < 4; t++)
#pragma unroll
      for (int c = 0; c < 4; c++){
        acc[t][c] = fmaf(lv[t].x, wv[c].x, acc[t][c]);
        acc[t][c] = fmaf(lv[t].y, wv[c].y, acc[t][c]);
        acc[t][c] = fmaf(lv[t].z, wv[c].z, acc[t][c]);
        acc[t][c] = fmaf(lv[t].w, wv[c].w, acc[t][c]);
      }
  }
  if (j0 < 128){
    // 3 boundary tokens (zero at batch start)
    int isStart = ((t0 & 4095) == 0);
    if (tid < 192){
      int e = tid >> 6, col = tid & 63;
      float v = 0.f;
      if (!isStart){
        const float* np = NT + (size_t)(t0 - 3 + e) * 64;
        float a2 = B2[j0 + col];
#pragma unroll 4
        for (int k = 0; k < 64; k += 4){
          float4 nv = *(const float4*)(np + k);
          float4 wv = *(const float4*)&wL[col * 68 + k];
          a2 = fmaf(nv.x, wv.x, fmaf(nv.y, wv.y, fmaf(nv.z, wv.z, fmaf(nv.w, wv.w, a2))));
        }
        v = a2;
      }
      xcs[e * 68 + col] = v;
    }
#pragma unroll
    for (int t = 0; t < 4; t++)
#pragma unroll
      for (int c = 0; c < 4; c++)
        xcs[(3 + tq * 4 + t) * 68 + cg + c * 16] = acc[t][c];
    __syncthreads();
#pragma unroll
    for (int c = 0; c < 4; c++){
      int lc = cg + c * 16;
      int ch = j0 + lc;
      float4 wv = *(const float4*)(cw + ch * 4);
      float bias = cb[ch];
#pragma unroll
      for (int t = 0; t < 4; t++){
        int row = 3 + tq * 4 + t;
        float a = bias;
        a = fmaf(wv.w, xcs[row * 68 + lc], a);
        a = fmaf(wv.z, xcs[(row - 1) * 68 + lc], a);
        a = fmaf(wv.y, xcs[(row - 2) * 68 + lc], a);
        a = fmaf(wv.x, xcs[(row - 3) * 68 + lc], a);
        size_t tg = t0 + tq * 4 + t;
        U[tg * 128 + ch] = a * sigmoidf_(a);
      }
    }
  } else {
#pragma unroll
    for (int t = 0; t < 4; t++){
      size_t tg = t0 + tq * 4 + t;
#pragma unroll
      for (int c = 0; c < 4; c++)
        Z[tg * 128 + (j0 - 128) + cg + c * 16] = acc[t][c];
    }
  }
}

// ---------------- x_proj only (both mambas); dt folded into scan kernels ----------------
__global__ __launch_bounds__(256) void k_xprojdt(
    const float* __restrict__ U0, const float* __restrict__ XW0, float* __restrict__ DBL0,
    const float* __restrict__ U1, const float* __restrict__ XW1, float* __restrict__ DBL1)
{
  __shared__ float xw[36 * 132];
  int bid = blockIdx.x;
  int m = bid >> 7, blk = bid & 127;
  const float* Up   = m ? U1   : U0;
  const float* XWp  = m ? XW1  : XW0;
  float* DBLp = m ? DBL1 : DBL0;
  int tid = threadIdx.x;
  for (int i = tid; i < 4608; i += 256)
    xw[(i >> 7) * 132 + (i & 127)] = XWp[i];
  __syncthreads();
  int slot = tid >> 2, jq = tid & 3;
  size_t tgA = (size_t)blk * 128 + slot;
  size_t tgB = tgA + 64;
  const float4* upA = (const float4*)(Up + tgA * 128);
  const float4* upB = (const float4*)(Up + tgB * 128);
  float accA[9], accB[9];
#pragma unroll
  for (int jj = 0; jj < 9; jj++){ accA[jj] = 0.f; accB[jj] = 0.f; }
  for (int k4 = 0; k4 < 32; k4++){
    float4 uA = upA[k4];
    float4 uB = upB[k4];
#pragma unroll
    for (int jj = 0; jj < 9; jj++){
      float4 w = *(const float4*)&xw[(jq * 9 + jj) * 132 + k4 * 4];
      accA[jj] = fmaf(w.x, uA.x, fmaf(w.y, uA.y, fmaf(w.z, uA.z, fmaf(w.w, uA.w, accA[jj]))));
      accB[jj] = fmaf(w.x, uB.x, fmaf(w.y, uB.y, fmaf(w.z, uB.z, fmaf(w.w, uB.w, accB[jj]))));
    }
  }
#pragma unroll
  for (int jj = 0; jj < 9; jj++){
    DBLp[tgA * 36 + jq * 9 + jj] = accA[jj];
    DBLp[tgB * 36 + jq * 9 + jj] = accB[jj];
  }
}

// ================= chunked parallel scan (4 states/thread, 32-token chunks) =================
// grid 2048 = 2m x 4b x 128chunk x 2cg. dt shared across q-lanes via shfl.
// FAST PATH: Alog = log(1..16) broadcast -> A[s] = -(s+1) exactly, so
// dA[s] = exp(-dt)^(s+1): ONE exp per (ch,t) + power chain replaces 4 quarter-rate exps.
// Guarded by a runtime check on A1; falls back to generic exp2 path if structure differs.
__global__ __launch_bounds__(256) void k_scanA(
    const float* __restrict__ DBL0, const float* __restrict__ U0, const float* __restrict__ AL0,
    const float* __restrict__ DTW0, const float* __restrict__ DTB0,
    const float* __restrict__ DBL1, const float* __restrict__ U1, const float* __restrict__ AL1,
    const float* __restrict__ DTW1, const float* __restrict__ DTB1,
    float* __restrict__ HF, float* __restrict__ AP)
{
  __shared__ float su[32 * 65], sB[16 * 36], sdtr[128];
  int bid = blockIdx.x;
  int cg = bid & 1;
  int c  = (bid >> 1) & 127;
  int b  = (bid >> 8) & 3;
  int m  = bid >> 10;
  const float* DBLp = m ? DBL1 : DBL0;
  const float* Up   = m ? U1   : U0;
  const float* ALp  = m ? AL1  : AL0;
  const float* DTWp = m ? DTW1 : DTW0;
  const float* DTBp = m ? DTB1 : DTB0;
  int tid = threadIdx.x;
  int lane = tid & 63, w = tid >> 6;
  int lcol = lane & 15, q = lane >> 4;
  int chL = w * 16 + lcol;
  int n = cg * 64 + chL;
  size_t base = (size_t)b * 4096 + c * 32;
  for (int i = tid; i < 2048; i += 256){
    int ch = i & 63, l = i >> 6;
    su[l * 65 + ch] = Up[(base + l) * 128 + cg * 64 + ch];
  }
  for (int i = tid; i < 512; i += 256){
    int s = i & 15, l = i >> 4;
    sB[s * 36 + l] = DBLp[(base + l) * 36 + 4 + s];
  }
  if (tid < 128){
    int l = tid >> 2, jj = tid & 3;
    sdtr[tid] = DBLp[(base + l) * 36 + jj];
  }
  const float LOG2E = 1.4426950408889634f;
  float A1[4];
  bool fastp = true;
#pragma unroll
  for (int j = 0; j < 4; j++){
    A1[j] = -__expf(ALp[n * 16 + q * 4 + j]) * LOG2E;
    float expe = -(float)(q * 4 + j + 1) * LOG2E;
    fastp = fastp && (fabsf(A1[j] - expe) <= 1e-3f);
  }
  float4 wdt = *(const float4*)(DTWp + n * 4);
  float bdt = DTBp[n];
  __syncthreads();
  float h[4] = {0.f, 0.f, 0.f, 0.f};
  float ap[4] = {1.f, 1.f, 1.f, 1.f};
#pragma unroll
  for (int l4 = 0; l4 < 8; l4++){
    int lq = l4 * 4 + q;
    float4 dq = *(const float4*)&sdtr[lq * 4];
    float xq = bdt;
    xq = fmaf(wdt.x, dq.x, xq); xq = fmaf(wdt.y, dq.y, xq);
    xq = fmaf(wdt.z, dq.z, xq); xq = fmaf(wdt.w, dq.w, xq);
    float dtq = softplus_(xq);
    float rq = __expf(-dtq);
    float dts[4], rs[4];
    dts[0] = __shfl(dtq, lcol);       rs[0] = __shfl(rq, lcol);
    dts[1] = __shfl(dtq, lcol + 16);  rs[1] = __shfl(rq, lcol + 16);
    dts[2] = __shfl(dtq, lcol + 32);  rs[2] = __shfl(rq, lcol + 32);
    dts[3] = __shfl(dtq, lcol + 48);  rs[3] = __shfl(rq, lcol + 48);
    float4 Bv[4];
#pragma unroll
    for (int j = 0; j < 4; j++) Bv[j] = *(const float4*)&sB[(q * 4 + j) * 36 + l4 * 4];
    if (fastp){
#pragma unroll
      for (int jj = 0; jj < 4; jj++){
        int l = l4 * 4 + jj;
        float dt = dts[jj], r = rs[jj];
        float u  = su[l * 65 + chL];
        float dtu = dt * u;
        float r2 = r * r, r4 = r2 * r2;
        float r8 = r4 * r4;
        float p0 = (q == 0) ? r : (q == 1) ? r4 * r : (q == 2) ? r8 * r : (r8 * r4) * r;
        float a0 = p0, a1 = a0 * r, a2 = a1 * r, a3 = a2 * r;
        h[0] = fmaf(a0, h[0], dtu * (&Bv[0].x)[jj]); ap[0] *= a0;
        h[1] = fmaf(a1, h[1], dtu * (&Bv[1].x)[jj]); ap[1] *= a1;
        h[2] = fmaf(a2, h[2], dtu * (&Bv[2].x)[jj]); ap[2] *= a2;
        h[3] = fmaf(a3, h[3], dtu * (&Bv[3].x)[jj]); ap[3] *= a3;
      }
    } else {
#pragma unroll
      for (int jj = 0; jj < 4; jj++){
        int l = l4 * 4 + jj;
        float dt = dts[jj];
        float u  = su[l * 65 + chL];
        float dtu = dt * u;
#pragma unroll
        for (int j = 0; j < 4; j++){
          float a = exp2f(dt * A1[j]);
          h[j] = fmaf(a, h[j], dtu * (&Bv[j].x)[jj]);
          ap[j] *= a;
        }
      }
    }
  }
  size_t o = ((size_t)((m * 4 + b) * 128 + c)) * 2048 + n * 16 + q * 4;
  *(float4*)&HF[o] = make_float4(h[0], h[1], h[2], h[3]);
  *(float4*)&AP[o] = make_float4(ap[0], ap[1], ap[2], ap[3]);
}

// scanB: affine chunk-combine h <- a*h + f, parallelized 8 lanes/row via shfl affine scan.
__global__ __launch_bounds__(256) void k_scanB(
    const float* __restrict__ HF, const float* __restrict__ AP, float* __restrict__ HIN)
{
  int gid = blockIdx.x * 256 + threadIdx.x;
  int r = gid >> 3;          // row 0..16383 = (m*4+b)*2048 + (n*16+s)
  int seg = gid & 7;         // 16-chunk segment
  int q = r >> 11;
  int p = r & 2047;
  size_t base = (size_t)q * 128 * 2048 + p + (size_t)seg * 16 * 2048;
  float a[16], f[16];
#pragma unroll
  for (int c8 = 0; c8 < 2; c8++){
#pragma unroll
    for (int j = 0; j < 8; j++){
      size_t o = base + (size_t)(c8 * 8 + j) * 2048;
      a[c8 * 8 + j] = AP[o];
      f[c8 * 8 + j] = HF[o];
    }
  }
  float A = 1.f, F = 0.f;
#pragma unroll
  for (int j = 0; j < 16; j++){ F = fmaf(a[j], F, f[j]); A *= a[j]; }
#pragma unroll
  for (int d = 1; d < 8; d <<= 1){
    float Au = __shfl_up(A, d, 8);
    float Fu = __shfl_up(F, d, 8);
    if (seg >= d){ F = fmaf(A, Fu, F); A = A * Au; }
  }
  float hin = __shfl_up(F, 1, 8);
  float h = (seg == 0) ? 0.f : hin;
#pragma unroll
  for (int j = 0; j < 16; j++){
    size_t o = base + (size_t)j * 2048;
    HIN[o] = h;
    h = fmaf(a[j], h, f[j]);
  }
}

__global__ __launch_bounds__(256) void k_scanC(
    const float* __restrict__ DBL0, const float* __restrict__ U0, const float* __restrict__ AL0,
    const float* __restrict__ DTW0, const float* __restrict__ DTB0,
    const float* __restrict__ D0, float* __restrict__ Y0,
    const float* __restrict__ DBL1, const float* __restrict__ U1, const float* __restrict__ AL1,
    const float* __restrict__ DTW1, const float* __restrict__ DTB1,
    const float* __restrict__ D1, float* __restrict__ Y1,
    const float* __restrict__ HIN)
{
  __shared__ float su[32 * 65], sB[16 * 36], sC[16 * 36], sdtr[128];
  int bid = blockIdx.x;
  int cg = bid & 1;
  int c  = (bid >> 1) & 127;
  int b  = (bid >> 8) & 3;
  int m  = bid >> 10;
  const float* DBLp = m ? DBL1 : DBL0;
  const float* Up   = m ? U1   : U0;
  const float* ALp  = m ? AL1  : AL0;
  const float* DTWp = m ? DTW1 : DTW0;
  const float* DTBp = m ? DTB1 : DTB0;
  const float* Dp   = m ? D1   : D0;
  float*       Yp   = m ? Y1   : Y0;
  int tid = threadIdx.x;
  int lane = tid & 63, w = tid >> 6;
  int lcol = lane & 15, q = lane >> 4;
  int chL = w * 16 + lcol;
  int n = cg * 64 + chL;
  size_t base = (size_t)b * 4096 + c * 32;
  for (int i = tid; i < 2048; i += 256){
    int ch = i & 63, l = i >> 6;
    su[l * 65 + ch] = Up[(base + l) * 128 + cg * 64 + ch];
  }
  for (int i = tid; i < 512; i += 256){
    int s = i & 15, l = i >> 4;
    size_t ob = (base + l) * 36;
    sB[s * 36 + l] = DBLp[ob + 4 + s];
    sC[s * 36 + l] = DBLp[ob + 20 + s];
  }
  if (tid < 128){
    int l = tid >> 2, jj = tid & 3;
    sdtr[tid] = DBLp[(base + l) * 36 + jj];
  }
  const float LOG2E = 1.4426950408889634f;
  float A1[4];
  bool fastp = true;
#pragma unroll
  for (int j = 0; j < 4; j++){
    A1[j] = -__expf(ALp[n * 16 + q * 4 + j]) * LOG2E;
    float expe = -(float)(q * 4 + j + 1) * LOG2E;
    fastp = fastp && (fabsf(A1[j] - expe) <= 1e-3f);
  }
  float4 wdt = *(const float4*)(DTWp + n * 4);
  float bdt = DTBp[n];
  float Dn = Dp[n];
  float4 hv = *(const float4*)&HIN[((size_t)((m * 4 + b) * 128 + c)) * 2048 + n * 16 + q * 4];
  float h[4] = {hv.x, hv.y, hv.z, hv.w};
  __syncthreads();
#pragma unroll
  for (int l4 = 0; l4 < 8; l4++){
    int lq = l4 * 4 + q;
    float4 dq = *(const float4*)&sdtr[lq * 4];
    float xq = bdt;
    xq = fmaf(wdt.x, dq.x, xq); xq = fmaf(wdt.y, dq.y, xq);
    xq = fmaf(wdt.z, dq.z, xq); xq = fmaf(wdt.w, dq.w, xq);
    float dtq = softplus_(xq);
    float rq = __expf(-dtq);
    float dts[4], rs[4];
    dts[0] = __shfl(dtq, lcol);       rs[0] = __shfl(rq, lcol);
    dts[1] = __shfl(dtq, lcol + 16);  rs[1] = __shfl(rq, lcol + 16);
    dts[2] = __shfl(dtq, lcol + 32);  rs[2] = __shfl(rq, lcol + 32);
    dts[3] = __shfl(dtq, lcol + 48);  rs[3] = __shfl(rq, lcol + 48);
    float4 Bv[4], Cv[4];
#pragma unroll
    for (int j = 0; j < 4; j++){
      Bv[j] = *(const float4*)&sB[(q * 4 + j) * 36 + l4 * 4];
      Cv[j] = *(const float4*)&sC[(q * 4 + j) * 36 + l4 * 4];
    }
    if (fastp){
#pragma unroll
      for (int jj = 0; jj < 4; jj++){
        int l = l4 * 4 + jj;
        float dt = dts[jj], r = rs[jj];
        float u  = su[l * 65 + chL];
        float dtu = dt * u;
        float r2 = r * r, r4 = r2 * r2;
        float r8 = r4 * r4;
        float p0 = (q == 0) ? r : (q == 1) ? r4 * r : (q == 2) ? r8 * r : (r8 * r4) * r;
        float a0 = p0, a1 = a0 * r, a2 = a1 * r, a3 = a2 * r;
        float p = 0.f;
        h[0] = fmaf(a0, h[0], dtu * (&Bv[0].x)[jj]); p = fmaf(h[0], (&Cv[0].x)[jj], p);
        h[1] = fmaf(a1, h[1], dtu * (&Bv[1].x)[jj]); p = fmaf(h[1], (&Cv[1].x)[jj], p);
        h[2] = fmaf(a2, h[2], dtu * (&Bv[2].x)[jj]); p = fmaf(h[2], (&Cv[2].x)[jj], p);
        h[3] = fmaf(a3, h[3], dtu * (&Bv[3].x)[jj]); p = fmaf(h[3], (&Cv[3].x)[jj], p);
        p += __shfl_xor(p, 16);
        p += __shfl_xor(p, 32);
        if (q == 0)
          Yp[(base + l) * 128 + n] = fmaf(u, Dn, p);
      }
    } else {
#pragma unroll
      for (int jj = 0; jj < 4; jj++){
        int l = l4 * 4 + jj;
        float dt = dts[jj];
        float u  = su[l * 65 + chL];
        float dtu = dt * u;
        float p = 0.f;
#pragma unroll
        for (int j = 0; j < 4; j++){
          float a = exp2f(dt * A1[j]);
          h[j] = fmaf(a, h[j], dtu * (&Bv[j].x)[jj]);
          p = fmaf(h[j], (&Cv[j].x)[jj], p);
        }
        p += __shfl_xor(p, 16);
        p += __shfl_xor(p, 32);
        if (q == 0)
          Yp[(base + l) * 128 + n] = fmaf(u, Dn, p);
      }
    }
  }
}

// ---------------- out_proj (both mambas): ((Y)*silu(Z)) @ W^T + softmax partials for m=1 ----------------
__global__ __launch_bounds__(256) void k_outproj(
    const float* __restrict__ Y0, const float* __restrict__ Zg0,
    const float* __restrict__ W0, float* __restrict__ OUT0,
    const float* __restrict__ Y1, const float* __restrict__ Zg1,
    const float* __restrict__ W1, float* __restrict__ OUT1,
    float* __restrict__ P)
{
  __shared__ float yl[16 * 128];
  __shared__ float wT[128 * 65];
  __shared__ float rM[256], rS[256];
  int m = blockIdx.y;
  const float* Y  = m ? Y1  : Y0;
  const float* Zg = m ? Zg1 : Zg0;
  const float* W  = m ? W1  : W0;
  float* OUT = m ? OUT1 : OUT0;
  int tid = threadIdx.x;
  size_t t0 = (size_t)blockIdx.x * 16;
  for (int i = tid; i < 2048; i += 256){
    float z = Zg[t0 * 128 + i];
    yl[i] = Y[t0 * 128 + i] * (z * sigmoidf_(z));
  }
  for (int i = tid; i < 8192; i += 256){
    int k = i & 127, j = i >> 7;
    wT[k * 65 + j] = W[j * 128 + k];
  }
  __syncthreads();
  int j = tid & 63;
  int tg = tid >> 6;
  float acc[4] = {0.f, 0.f, 0.f, 0.f};
  for (int k = 0; k < 128; k += 4){
    float w0 = wT[k * 65 + j], w1 = wT[(k+1) * 65 + j];
    float w2 = wT[(k+2) * 65 + j], w3 = wT[(k+3) * 65 + j];
#pragma unroll
    for (int t = 0; t < 4; t++){
      float4 yv = *(const float4*)&yl[(tg * 4 + t) * 128 + k];
      acc[t] = fmaf(w0, yv.x, fmaf(w1, yv.y, fmaf(w2, yv.z, fmaf(w3, yv.w, acc[t]))));
    }
  }
#pragma unroll
  for (int t = 0; t < 4; t++)
    OUT[(t0 + tg * 4 + t) * 64 + j] = acc[t];
  if (m == 1){
    float mx = fmaxf(fmaxf(acc[0], acc[1]), fmaxf(acc[2], acc[3]));
    float sm = __expf(acc[0] - mx) + __expf(acc[1] - mx) + __expf(acc[2] - mx) + __expf(acc[3] - mx);
    rM[tid] = mx; rS[tid] = sm;
    __syncthreads();
    if (tid < 64){
      float M = rM[tid], S = rS[tid];
      for (int p2 = 1; p2 < 4; p2++){
        float m2 = rM[p2 * 64 + tid], s2 = rS[p2 * 64 + tid];
        float Mn = fmaxf(M, m2);
        S = S * __expf(M - Mn) + s2 * __expf(m2 - Mn);
        M = Mn;
      }
      P[((size_t)blockIdx.x * 64 + tid) * 2] = M;
      P[((size_t)blockIdx.x * 64 + tid) * 2 + 1] = S;
    }
  }
}

// ---------------- combine (+softmax finalize) + transpose to (b,c,64,64) ----------------
// P holds 256 partials per (b, j) (one per 16-token outproj block).
__global__ void k_combine(const float* __restrict__ T, const float* __restrict__ MAIN,
                          const float* __restrict__ G, const float* __restrict__ P,
                          float* __restrict__ FEAT){
  int bid = blockIdx.x;
  int b = bid >> 6, row = bid & 63;
  int tid = threadIdx.x;
  __shared__ float tile[64 * 65];
  __shared__ float sM[256], sS[256], Mv[64], iSv[64];
  {
    int j2 = tid & 63, part = tid >> 6;
    float M = -3.4e38f, S = 0.f;
    for (int i = 0; i < 64; i++){
      int pb = part + i * 4;               // 0..255
      int idx = ((b * 256 + pb) * 64 + j2) * 2;
      float m2 = P[idx], s2 = P[idx + 1];
      float Mn = fmaxf(M, m2);
      S = S * __expf(M - Mn) + s2 * __expf(m2 - Mn);
      M = Mn;
    }
    sM[tid] = M; sS[tid] = S;
  }
  __syncthreads();
  if (tid < 64){
    float M = sM[tid], S = sS[tid];
    for (int p = 1; p < 4; p++){
      float m2 = sM[p * 64 + tid], s2 = sS[p * 64 + tid];
      float Mn = fmaxf(M, m2);
      S = S * __expf(M - Mn) + s2 * __expf(m2 - Mn);
      M = Mn;
    }
    Mv[tid] = M; iSv[tid] = 1.f / S;
  }
  __syncthreads();
  int j = tid & 63, ls = tid >> 6;
  float M = Mv[j], invS = iSv[j];
  size_t lbase = (size_t)b * 4096 + row * 64;
  for (int i = 0; i < 16; i++){
    int col = ls + i * 4;
    size_t off = (lbase + col) * 64 + j;
    float g = __expf(G[off] - M) * invS;
    tile[col * 65 + j] = T[off] + g * MAIN[off];
  }
  __syncthreads();
  int colw = tid & 63, jr = tid >> 6;
  for (int jj = jr; jj < 64; jj += 4)
    FEAT[(((size_t)b * 64 + jj) * 64 + row) * 64 + colw] = tile[colw * 65 + jj];
}

// ---------------- host launcher ----------------
extern "C" void kernel_launch(void* const* d_in, const int* in_sizes, int n_in,
                              void* d_out, int out_size, void* d_ws, size_t ws_size,
                              hipStream_t stream) {
  // workspace layout (float offsets)
  const size_t P1A = 0, P1B = 4326400;
  const size_t MB0 = 0, MB1 = 10027008;
  const size_t O_LN = 0, O_XC = 1048576, O_Z = 3145728, O_U = 5242880,
               O_DBL = 9437184;
  const size_t TOK = 20054016, OUT0 = 21102592, OUT1 = 22151168;
  const size_t FEAT = 23208448;
  const size_t P3A = 4194304, P3B = 8520704;
  const size_t WSET = 19000000;         // 8 x 18432 floats: cb1h,cb1l,cb2h,cb2l,sw1h,sw1l,sw2h,sw2l
  const size_t PADN = 2163200;
  const size_t SMP = 0;                 // softmax partials: 1024 x 64 x 2 floats
  const size_t W2_0 = 21102592, B2_0 = 21118976, W2_1 = 21119232, B2_1 = 21135616;
  const size_t TOTAL = 24257024;
  if (ws_size < TOTAL * 4) return;

  float* ws = (float*)d_ws;
  const float* X   = (const float*)d_in[0];
  const float* CB1 = (const float*)d_in[1];
  const float* CB2 = (const float*)d_in[2];
  const float* SW1 = (const float*)d_in[3];
  const float* SW2 = (const float*)d_in[4];
  const float* LNW[2] = { (const float*)d_in[5], (const float*)d_in[7] };
  const float* LNB[2] = { (const float*)d_in[6], (const float*)d_in[8] };
  const float *INW[2], *CW[2], *CBb[2], *XPW[2], *DTW[2], *DTB[2], *AL[2], *DD[2], *OW[2];
  for (int m = 0; m < 2; m++){
    int p = 9 + m * 9;
    INW[m] = (const float*)d_in[p + 0];
    CW[m]  = (const float*)d_in[p + 1];
    CBb[m] = (const float*)d_in[p + 2];
    XPW[m] = (const float*)d_in[p + 3];
    DTW[m] = (const float*)d_in[p + 4];
    DTB[m] = (const float*)d_in[p + 5];
    AL[m]  = (const float*)d_in[p + 6];
    DD[m]  = (const float*)d_in[p + 7];
    OW[m]  = (const float*)d_in[p + 8];
  }

  u16* wset[8];
  for (int k = 0; k < 8; k++) wset[k] = (u16*)(ws + WSET + (size_t)k * 18432);

  u16* p1ah = (u16*)(ws + P1A); u16* p1al = p1ah + PADN * 2;
  u16* p1bh = (u16*)(ws + P1B); u16* p1bl = p1bh + PADN * 2;
  u16* p3ah = (u16*)(ws + P3A); u16* p3al = p3ah + PADN * 2;
  u16* p3bh = (u16*)(ws + P3B); u16* p3bl = p3bh + PADN * 2;

  // ---- setup (weight swizzles + LN fold) + prep of X, one launch ----
  k_setup<<<1097, 256, 0, stream>>>(CB1, wset[0], wset[1], CB2, wset[2], wset[3],
                                    SW1, wset[4], wset[5], SW2, wset[6], wset[7],
                                    INW[0], LNW[0], LNB[0], ws + W2_0, ws + B2_0,
                                    INW[1], LNW[1], LNB[1], ws + W2_1, ws + B2_1,
                                    X, p1ah, p1al, p1bh, p1bl);

  // ---- phase 1: conv block (MFMA) + fused tokenize/LN ----
  k_convm<<<dim3(8, 16, 4), 256, 0, stream>>>(p1ah, p1al, wset[0], wset[1], nullptr,
                                              p1bh, p1bl, nullptr, nullptr, nullptr, 0);
  k_convm<<<dim3(8, 16, 4), 256, 0, stream>>>(p1bh, p1bl, wset[2], wset[3], X,
                                              nullptr, nullptr, nullptr,
                                              ws + TOK, ws + MB0 + O_LN, 2);

  // ---- phase 2: mamba x2 ----
  k_inprojdw<<<dim3(256, 4, 2), 256, 0, stream>>>(
      ws + MB0 + O_LN,
      ws + W2_0, ws + B2_0, ws + MB0 + O_U, ws + MB0 + O_Z, CW[0], CBb[0],
      ws + W2_1, ws + B2_1, ws + MB1 + O_U, ws + MB1 + O_Z, CW[1], CBb[1]);
  k_xprojdt<<<256, 256, 0, stream>>>(
      ws + MB0 + O_U, XPW[0], ws + MB0 + O_DBL,
      ws + MB1 + O_U, XPW[1], ws + MB1 + O_DBL);

  // scan buffers (2M floats each, 32-token chunks -> 1024 chunk-rows x 2048):
  // HF -> MB0+O_XC (overwritten by Y0 in scanC, after scanB consumed it)
  // AP -> MB1+O_XC (overwritten by Y1 in scanC, after scanB consumed it)
  // HIN -> OUT1..FEAT span (dead until k_outproj / k_combine)
  float* HF  = ws + MB0 + O_XC;
  float* AP  = ws + MB1 + O_XC;
  float* HIN = ws + OUT1;

  k_scanA<<<2048, 256, 0, stream>>>(
      ws + MB0 + O_DBL, ws + MB0 + O_U, AL[0], DTW[0], DTB[0],
      ws + MB1 + O_DBL, ws + MB1 + O_U, AL[1], DTW[1], DTB[1],
      HF, AP);
  k_scanB<<<512, 256, 0, stream>>>(HF, AP, HIN);
  k_scanC<<<2048, 256, 0, stream>>>(
      ws + MB0 + O_DBL, ws + MB0 + O_U, AL[0], DTW[0], DTB[0], DD[0], ws + MB0 + O_XC,
      ws + MB1 + O_DBL, ws + MB1 + O_U, AL[1], DTW[1], DTB[1], DD[1], ws + MB1 + O_XC,
      HIN);

  k_outproj<<<dim3(1024, 2), 256, 0, stream>>>(
      ws + MB0 + O_XC, ws + MB0 + O_Z, OW[0], ws + OUT0,
      ws + MB1 + O_XC, ws + MB1 + O_Z, OW[1], ws + OUT1,
      ws + SMP);

  k_combine<<<256, 256, 0, stream>>>(ws + TOK, ws + OUT0, ws + OUT1, ws + SMP, ws + FEAT);

  // ---- phase 3: fused upsample+prep + conv block (MFMA) ----
  k_prepup<<<dim3(130, 4), 256, 0, stream>>>(ws + FEAT, p3ah, p3al, p3bh, p3bl);
  k_convm<<<dim3(8, 16, 4), 256, 0, stream>>>(p3ah, p3al, wset[4], wset[5], nullptr,
                                              p3bh, p3bl, nullptr, nullptr, nullptr, 0);
  k_convm<<<dim3(8, 16, 4), 256, 0, stream>>>(p3bh, p3bl, wset[6], wset[7], nullptr,
                                              nullptr, nullptr, (float*)d_out,
                                              nullptr, nullptr, 1);
}